// Round 10
// baseline (1240.608 us; speedup 1.0000x reference)
//
#include <hip/hip_runtime.h>
#include <math.h>

// Problem constants: B=64, N=64, D=6, L=32, T=2048
#define TB 2048
#define LL 32
#define NP 64
#define DD 6
#define BB 64
#define CW 16           // columns per macro-step
#define MSTEPS (TB/CW)  // 128
#define NL 16           // lanes per DP problem
#define RW 2            // rows per lane (L = 16*2 = 32)
#define XSTRIDE 20      // floats per 16-float x block (80 B, bank-covering)

// ABLATION ROUND. R0-R8: five structural theories (shuffle latency, LDS
// throughput, LDS latency, instruction bloat, TLP starvation) each moved
// time <10%; measured ~5700 CU-cyc/mstep vs ~3200 issue-floor. This round
// decomposes the mstep cost with 5 within-probe variants (rocprof gives
// per-dispatch dur_us). MODE: 0=FULL (canonical, launched last, writes the
// real output), 1=NOSTORE (asm-sink keeps DP chain live), 2=NOLDS (x tile
// from registers, no in-loop ds_read), 3=NODPP (up=Y, no cross-lane),
// 4=NODEP (same instr count, loop-carried a0/a1/diag replaced by per-mstep
// constants -> columns independent given Y's).

__device__ __forceinline__ float dpp_shr1(float v) {
    const int i = __float_as_int(v);
    // row_shr:1, all rows/banks, bound_ctrl=false (lane0 of row keeps old)
    const int r = __builtin_amdgcn_update_dpp(i, i, 0x111, 0xF, 0xF, false);
    return __int_as_float(r);
}

#define STEPX(XV, Y) {                                                    \
    float up;                                                             \
    if constexpr (MODE == 3) up = (Y); else up = dpp_shr1(Y);             \
    const float t0 = p0 - (XV);                                           \
    const float t1 = p1 - (XV);                                           \
    const float c0 = t0 * t0;                                             \
    if constexpr (MODE == 4) {                                            \
        const float f0 = fmaf(w, fminf(fminf(B0, up), B1), c0);           \
        const float v0 = k0 ? c0 : f0;                                    \
        const float v1 = fmaf(w, fminf(fminf(B2, v0), B3), t1 * t1);      \
        Y = v1;                                                           \
    } else {                                                              \
        const float f0 = fmaf(w, fminf(fminf(a0, up), diag), c0);         \
        const float v0 = k0 ? c0 : f0;                                    \
        const float v1 = fmaf(w, fminf(fminf(a1, v0), a0), t1 * t1);      \
        a0 = v0; a1 = v1; diag = up;                                      \
        Y = v1;                                                           \
    }                                                                     \
}

template<int MODE>
__global__ __launch_bounds__(256) void dtw_k(
    const float* __restrict__ x,      // (B, D, T)
    const float* __restrict__ patts,  // (N, L)
    const float* __restrict__ wptr,   // scalar
    float* __restrict__ out)          // (B, N, D, T)
{
    __shared__ float xs[MSTEPS * XSTRIDE];    // 10240 B

    const int bid  = blockIdx.x;      // B*D*4 = 1536 blocks
    const int quad = bid & 3;         // which 16 of the 64 patterns
    const int bd   = bid >> 2;        // b*D + d
    const int tid  = threadIdx.x;     // 0..255

    const float INF = __builtin_inff();

    const float4* xrow = (const float4*)(x + (size_t)bd * TB);
    #pragma unroll
    for (int i = 0; i < 2; ++i) {
        const int idx = tid + i * 256;            // float4 index 0..511
        *(float4*)(xs + (idx >> 2) * XSTRIDE + (idx & 3) * 4) = xrow[idx];
    }
    __syncthreads();

    const int g = tid >> 4;           // group 0..15 (one pattern each)
    const int k = tid & 15;           // lane within group (rows 2k, 2k+1)
    const int n = quad * 16 + g;

    const float w = wptr[0];
    const float2 pv = *(const float2*)(patts + n * LL + k * RW);
    const float p0 = pv.x, p1 = pv.y;

    // NODEP constants (runtime values so nothing folds away).
    const float B0 = p0 * 0.5f, B1 = p1 * 0.5f, B2 = p0 * 0.25f, B3 = p1 * 0.25f;

    const int b = bd / DD, d = bd - (bd / DD) * DD;
    float* __restrict__ orow = out + (((size_t)b * NP + n) * DD + d) * TB;

    const bool k0 = (k == 0), kl = (k == NL - 1);

    float a0 = INF, a1 = INF;
    float diag = INF;
    float y0 = INF, y1 = INF, y2 = INF, y3 = INF,
          y4 = INF, y5 = INF, y6 = INF, y7 = INF,
          y8 = INF, y9 = INF, y10 = INF, y11 = INF,
          y12 = INF, y13 = INF, y14 = INF, y15 = INF;

    // NOLDS: pre-loop register x tile (tile 0), reused every mstep.
    float4 rA, rB, rC, rD;
    if constexpr (MODE == 2) {
        rA = *(const float4*)(xs + 0);
        rB = *(const float4*)(xs + 4);
        rC = *(const float4*)(xs + 8);
        rD = *(const float4*)(xs + 12);
    }

    for (int m = 0; m < MSTEPS + NL - 1; ++m) {
        const int q = m - k;
        const bool valid = ((unsigned)q < (unsigned)MSTEPS);

        float4 xA, xB, xC, xD;
        if constexpr (MODE == 2) {
            xA = rA; xB = rB; xC = rC; xD = rD;
        } else {
            const int qq = valid ? q : 0;
            const float* xb = xs + qq * XSTRIDE;
            xA = *(const float4*)(xb + 0);
            xB = *(const float4*)(xb + 4);
            xC = *(const float4*)(xb + 8);
            xD = *(const float4*)(xb + 12);
        }

        STEPX(xA.x, y0)  STEPX(xA.y, y1)  STEPX(xA.z, y2)  STEPX(xA.w, y3)
        STEPX(xB.x, y4)  STEPX(xB.y, y5)  STEPX(xB.z, y6)  STEPX(xB.w, y7)
        STEPX(xC.x, y8)  STEPX(xC.y, y9)  STEPX(xC.z, y10) STEPX(xC.w, y11)
        STEPX(xD.x, y12) STEPX(xD.y, y13) STEPX(xD.z, y14) STEPX(xD.w, y15)

        if constexpr (MODE != 1) {
            if (kl && valid) {
                float4* op = (float4*)(orow + q * CW);
                op[0] = make_float4(__builtin_amdgcn_sqrtf(y0),
                                    __builtin_amdgcn_sqrtf(y1),
                                    __builtin_amdgcn_sqrtf(y2),
                                    __builtin_amdgcn_sqrtf(y3));
                op[1] = make_float4(__builtin_amdgcn_sqrtf(y4),
                                    __builtin_amdgcn_sqrtf(y5),
                                    __builtin_amdgcn_sqrtf(y6),
                                    __builtin_amdgcn_sqrtf(y7));
                op[2] = make_float4(__builtin_amdgcn_sqrtf(y8),
                                    __builtin_amdgcn_sqrtf(y9),
                                    __builtin_amdgcn_sqrtf(y10),
                                    __builtin_amdgcn_sqrtf(y11));
                op[3] = make_float4(__builtin_amdgcn_sqrtf(y12),
                                    __builtin_amdgcn_sqrtf(y13),
                                    __builtin_amdgcn_sqrtf(y14),
                                    __builtin_amdgcn_sqrtf(y15));
            }
        }
    }

    if constexpr (MODE == 1) {
        // Keep the entire DP chain live without stores (rule #17).
        asm volatile("" :: "v"(y0), "v"(y1), "v"(y2), "v"(y3),
                           "v"(y4), "v"(y5), "v"(y6), "v"(y7),
                           "v"(y8), "v"(y9), "v"(y10), "v"(y11),
                           "v"(y12), "v"(y13), "v"(y14), "v"(y15));
    }
}

extern "C" void kernel_launch(void* const* d_in, const int* in_sizes, int n_in,
                              void* d_out, int out_size, void* d_ws, size_t ws_size,
                              hipStream_t stream) {
    const float* x     = (const float*)d_in[0];
    const float* patts = (const float*)d_in[1];
    const float* wptr  = (const float*)d_in[2];
    float* out = (float*)d_out;

    dim3 grid(BB * DD * 4);   // 1536 blocks
    dim3 block(256);          // 16 groups of 16 lanes

    // Ablation dispatches (write garbage / nothing), then canonical FULL
    // last so d_out is correct and deterministic.
    dtw_k<1><<<grid, block, 0, stream>>>(x, patts, wptr, out);  // NOSTORE
    dtw_k<2><<<grid, block, 0, stream>>>(x, patts, wptr, out);  // NOLDS
    dtw_k<3><<<grid, block, 0, stream>>>(x, patts, wptr, out);  // NODPP
    dtw_k<4><<<grid, block, 0, stream>>>(x, patts, wptr, out);  // NODEP
    dtw_k<0><<<grid, block, 0, stream>>>(x, patts, wptr, out);  // FULL
}